// Round 1
// 538.929 us; speedup vs baseline: 1.5057x; 1.5057x over previous
//
#include <hip/hip_runtime.h>

// Fused 5x5 SAME conv + FastLIF + FastLI scan over T — FLOAT64 internal math.
// x: [T=256, 1, H=512, W=512] fp32, kernel: [1,1,5,5] fp32, out: [T,1,H,W] fp32.
//
// NUMERICS (unchanged from the passing R3 kernel): conv accumulation + LIF/LI
// state all in double, identical FMA ordering, inputs widened f32->f64 exactly
// at LDS staging, output rounded to f32 at store. Zero halo handled by
// never-overwritten zero registers for OOB lanes.
//
// R4 RESTRUCTURE (latency/sync-bound per rocprof: VALUBusy 14%, HBM 12%,
// ~4900 cy/timestep vs ~1100 cy of actual work): the old loop's
// __syncthreads() forced a full vmcnt(0) drain every timestep, serially
// exposing ~900-cycle HBM latency per step. New structure:
//   - register-staged prefetch (issue loads for t+2 at top of iter t,
//     ds_write the x[t+1] registers at the bottom -> ~1.5 iters of slack)
//   - raw s_barrier with lgkmcnt(0) only (no vmcnt drain) + sched_barrier
//     fences so global prefetch loads stay in flight ACROSS the barrier
//   - t-loop unrolled by 2 so buffers/registers are statically named
//   - nontemporal output stores (write-once data; keep L2 for halo reuse)

namespace {

constexpr int T_STEPS = 256;
constexpr int H = 512;
constexpr int W = 512;
constexpr int HW = H * W;
constexpr int TW = 64;            // tile width
constexpr int TH = 8;             // tile height
constexpr int HALO_W = TW + 4;    // 68
constexpr int HALO_H = TH + 4;    // 12
constexpr int NLOAD = HALO_W * HALO_H;  // 816 doubles per tile per timestep
constexpr int NTHREADS = 256;

__device__ __forceinline__ void sync_nodrain_vm() {
    // __syncthreads() emits s_waitcnt vmcnt(0) lgkmcnt(0) before s_barrier,
    // draining the in-flight global prefetch every timestep. We only need
    // LDS visibility across the block: drain lgkm (ds_writes complete),
    // barrier, and scheduling fences so nothing is reordered across it.
    __builtin_amdgcn_sched_barrier(0);
    asm volatile("s_waitcnt lgkmcnt(0)");
    __builtin_amdgcn_s_barrier();
    __builtin_amdgcn_sched_barrier(0);
}

__global__ __launch_bounds__(NTHREADS, 2)
void snn_fused(const float* __restrict__ x, const float* __restrict__ kern,
               float* __restrict__ out) {
    #pragma clang fp contract(off)

    __shared__ double smem[2][NLOAD];   // 2 x 816 x 8B = 13056 B

    const int tid = threadIdx.x;
    const int w0 = blockIdx.x * TW;
    const int h0 = blockIdx.y * TH;

    // 5x5 weights, widened to f64 (exact). Wave-uniform -> SGPR pairs.
    double wgt[25];
    #pragma unroll
    for (int i = 0; i < 25; ++i) wgt[i] = (double)kern[i];

    // Staging slots precomputed once; only the x base pointer moves per step.
    int  goff[4];
    bool gval[4];
    #pragma unroll
    for (int i = 0; i < 4; ++i) {
        int idx = tid + i * NTHREADS;
        int lh = idx / HALO_W;
        int lwp = idx - lh * HALO_W;
        int gh = h0 - 2 + lh;
        int gw = w0 - 2 + lwp;
        goff[i] = gh * W + gw;
        gval[i] = (idx < NLOAD) &&
                  ((unsigned)gh < (unsigned)H) && ((unsigned)gw < (unsigned)W);
    }

    // Two adjacent output rows per thread (share 4 of 6 halo rows).
    const int lw  = tid & (TW - 1);       // 0..63
    const int lh0 = (tid >> 6) * 2;       // 0,2,4,6
    const int gh0 = h0 + lh0;

    double s1a = 0.0, s2a = 0.0;   // row gh0
    double s1b = 0.0, s2b = 0.0;   // row gh0+1

    // Prefetch register sets. OOB lanes are initialized to 0 and NEVER
    // overwritten (gval is loop-invariant), so the zero-halo comes for free.
    float rA[4], rB[4];
    #pragma unroll
    for (int i = 0; i < 4; ++i) { rA[i] = 0.0f; rB[i] = 0.0f; }

    // Issue 4 exec-masked global loads; no consumer here, so the compiler's
    // vmcnt wait lands at the (much later) stage_write, not at the issue.
    auto issue_loads = [&](int t, float* r) {
        const float* xt = x + (size_t)t * HW;
        #pragma unroll
        for (int i = 0; i < 4; ++i) {
            if (gval[i]) r[i] = xt[goff[i]];
        }
    };

    // Widen to f64 and write to LDS (compiler inserts the counted vmcnt wait
    // for the register set right here).
    auto stage_write = [&](double* buf, const float* r) {
        #pragma unroll
        for (int i = 0; i < 4; ++i) {
            int idx = tid + i * NTHREADS;
            if (idx < NLOAD) buf[idx] = (double)r[i];
        }
    };

    // 5x5 conv (two adjacent rows, f64 FMA, EXACT same accumulation order as
    // the verified R3 kernel) + LIF/LI state update + output store.
    auto step = [&](const double* buf, int t) {
        #pragma clang fp contract(off)
        const double* sm = buf + lh0 * HALO_W + lw;
        double acc0 = 0.0, acc1 = 0.0;
        #pragma unroll
        for (int kh = 0; kh < 6; ++kh) {
            const double* row = sm + kh * HALO_W;
            double c0 = row[0], c1 = row[1], c2 = row[2], c3 = row[3], c4 = row[4];
            if (kh < 5) {
                acc0 = __builtin_fma(wgt[kh * 5 + 0], c0, acc0);
                acc0 = __builtin_fma(wgt[kh * 5 + 1], c1, acc0);
                acc0 = __builtin_fma(wgt[kh * 5 + 2], c2, acc0);
                acc0 = __builtin_fma(wgt[kh * 5 + 3], c3, acc0);
                acc0 = __builtin_fma(wgt[kh * 5 + 4], c4, acc0);
            }
            if (kh >= 1) {
                acc1 = __builtin_fma(wgt[(kh - 1) * 5 + 0], c0, acc1);
                acc1 = __builtin_fma(wgt[(kh - 1) * 5 + 1], c1, acc1);
                acc1 = __builtin_fma(wgt[(kh - 1) * 5 + 2], c2, acc1);
                acc1 = __builtin_fma(wgt[(kh - 1) * 5 + 3], c3, acc1);
                acc1 = __builtin_fma(wgt[(kh - 1) * 5 + 4], c4, acc1);
            }
        }

        {
            double v = 0.85 * s1a + acc0;
            double spk = (v >= 2.0) ? 1.0 : 0.0;
            s1a = v - spk * 2.0;
            s2a = 0.9 * s2a + spk;
        }
        {
            double v = 0.85 * s1b + acc1;
            double spk = (v >= 2.0) ? 1.0 : 0.0;
            s1b = v - spk * 2.0;
            s2b = 0.9 * s2b + spk;
        }

        float* outp = out + (size_t)t * HW + (size_t)gh0 * W + (w0 + lw);
        __builtin_nontemporal_store((float)s2a, outp);
        __builtin_nontemporal_store((float)s2b, outp + W);
    };

    // ---- pipeline prologue: buf0 <- x[0]; x[1] left in flight in rB.
    issue_loads(0, rA);
    issue_loads(1, rB);
    stage_write(smem[0], rA);
    sync_nodrain_vm();

    // ---- steady state: 2 timesteps per iteration.
    // Invariant entering iter tb (t0 = 2*tb): smem[0] holds x[t0] (all waves,
    // barrier'd), rB holds x[t0+1] (in flight or arrived).
    for (int tb = 0; tb < 127; ++tb) {
        const int t0 = 2 * tb;

        // even timestep t0: compute from smem[0]
        issue_loads(t0 + 2, rA);        // ~1.5 iterations of latency slack
        step(smem[0], t0);
        stage_write(smem[1], rB);       // rB = x[t0+1]
        sync_nodrain_vm();

        // odd timestep t0+1: compute from smem[1]
        issue_loads(t0 + 3, rB);
        step(smem[1], t0 + 1);
        stage_write(smem[0], rA);       // rA = x[t0+2]
        sync_nodrain_vm();
    }

    // ---- tail: t = 254, 255 (no further prefetch)
    step(smem[0], 254);
    stage_write(smem[1], rB);           // rB = x[255]
    sync_nodrain_vm();
    step(smem[1], 255);
}

}  // namespace

extern "C" void kernel_launch(void* const* d_in, const int* in_sizes, int n_in,
                              void* d_out, int out_size, void* d_ws, size_t ws_size,
                              hipStream_t stream) {
    const float* x    = (const float*)d_in[0];
    const float* kern = (const float*)d_in[1];
    float* out        = (float*)d_out;

    dim3 grid(W / TW, H / TH);  // (8, 64) = 512 blocks -> 2 blocks/CU
    snn_fused<<<grid, dim3(NTHREADS), 0, stream>>>(x, kern, out);
}